// Round 11
// baseline (16915.225 us; speedup 1.0000x reference)
//
#include <hip/hip_runtime.h>

#define T_STEPS 4096
#define N_RES   2048
#define N_IN    64
#define N_OUT   64
#define LEAK    0.3f
#define NOISE_S 0.01f

#define NWG     512      // reservoir WGs: ONE WAVE each, 4 rows
#define RPW     4        // rows per WG/wave (= one 16B tagged group)

typedef unsigned int uint32x4 __attribute__((ext_vector_type(4)));

// ---------------------------------------------------------------------------
// Kernel 1: it[t][n] = dot(u[t,:], W_in[n,:]) + 0.01*noise[t][n]
// ---------------------------------------------------------------------------
__global__ __launch_bounds__(256) void input_terms_kernel(
    const float* __restrict__ u, const float* __restrict__ noise,
    const float* __restrict__ W_in, float* __restrict__ it) {
  const int t = blockIdx.x;
  const int tid = threadIdx.x;
  __shared__ float su[N_IN];
  if (tid < N_IN) su[tid] = u[(size_t)t * N_IN + tid];
  __syncthreads();
  #pragma unroll
  for (int k = 0; k < N_RES / 256; ++k) {
    const int n = tid + 256 * k;
    const float4* wr = reinterpret_cast<const float4*>(W_in + (size_t)n * N_IN);
    float acc = 0.f;
    #pragma unroll
    for (int j = 0; j < N_IN / 4; ++j) {
      float4 w4 = wr[j];
      acc = fmaf(w4.x, su[4 * j + 0], acc);
      acc = fmaf(w4.y, su[4 * j + 1], acc);
      acc = fmaf(w4.z, su[4 * j + 2], acc);
      acc = fmaf(w4.w, su[4 * j + 3], acc);
    }
    it[(size_t)t * N_RES + n] = acc + NOISE_S * noise[(size_t)t * N_RES + n];
  }
}

// ---------------------------------------------------------------------------
// Kernel 2: WAVE-AUTONOMOUS recurrence. 512 WGs x 64 threads (one wave),
// 2 WGs/CU. WG g owns rows [4g, 4g+4); W rows in 32 KB LDS.
//
// ZERO barriers. Lane l's FMA operands for chunk j are exactly the 16B
// group (l + 64j): poll them straight into REGISTERS (no LDS state buffer).
// A chunk is consumed (16 fmaf x 4 rows) as soon as ALL lanes see its tag —
// compute overlaps arrival skew. Reduce, tanh/leak on lanes 0-3 (sold = own
// register from previous step), pack via 3 shuffles, lane 0 fires ONE
// tagged dwordx4 (single producer per group -> groups flip atomically;
// R9's two-producer groups caused partial flips + re-poll storms).
//
// Tag protocol (unchanged, now fully async): state word = fp32 bits with
// low 2 mantissa bits = (step & 3). A wave stores s_{t+1} only after
// consuming ALL of s_t; therefore when any wave reaches t+2 and overwrites
// buffer parity t&1, every wave has finished reading s_t. Tags in a buffer
// differ by 2 mod 4 from the sought tag -> stale reads are detected; re-
// reads are stable (slot can't advance past t+1 while we're still at t).
// s_0 = memset zeros with tag 0 = poll target at t=0 -> immediate, zeros.
// ---------------------------------------------------------------------------
__global__ __launch_bounds__(64, 1) void reservoir_kernel(
    const float* __restrict__ W, float* __restrict__ it,
    unsigned int* sbuf) {
  const int wg = blockIdx.x;      // 0..511
  const int lane = threadIdx.x;   // 0..63
  const int r0 = wg * RPW;        // this wave's 4 rows

  __shared__ float Wl[RPW * N_RES];  // 32 KB

  // Stage the 4 W rows into LDS (coalesced float4; single wave, no barrier
  // needed — wave-internal lgkmcnt ordering suffices).
  {
    const float4* Wg = reinterpret_cast<const float4*>(W + (size_t)r0 * N_RES);
    float4* Wd = reinterpret_cast<float4*>(Wl);
    #pragma unroll
    for (int k = 0; k < RPW * N_RES / 4 / 64; ++k)
      Wd[lane + 64 * k] = Wg[lane + 64 * k];
  }
  const float4* W0 = reinterpret_cast<const float4*>(Wl + 0 * N_RES);
  const float4* W1 = reinterpret_cast<const float4*>(Wl + 1 * N_RES);
  const float4* W2 = reinterpret_cast<const float4*>(Wl + 2 * N_RES);
  const float4* W3 = reinterpret_cast<const float4*>(Wl + 3 * N_RES);

  float itv = (lane < RPW) ? it[r0 + lane] : 0.f;  // input term for step 0
  float sprev = 0.f;                               // own row state (lanes 0-3)

  for (unsigned int t = 0; t < T_STEPS; ++t) {
    const unsigned int rt = t & 3u;          // tag of s_t
    const unsigned int tg = (t + 1) & 3u;    // tag of s_{t+1}
    const char* p0 = (const char*)(sbuf + (t & 1) * N_RES) + lane * 16;
    const char* p1 = p0 + 4096;

    uint32x4 V0, V1, V2, V3, V4, V5, V6, V7;
    float a0 = 0.f, a1 = 0.f, a2 = 0.f, a3 = 0.f;
    unsigned int need = 0xFFu;

    while (need) {
      // Issue loads ONLY for pending chunks (sweep traffic shrinks as
      // groups land), then one vmcnt(0); "+v" ties the checks after it.
      if (need &   1u) asm volatile("global_load_dwordx4 %0, %1, off sc0 sc1" : "=v"(V0) : "v"(p0));
      if (need &   2u) asm volatile("global_load_dwordx4 %0, %1, off offset:1024 sc0 sc1" : "=v"(V1) : "v"(p0));
      if (need &   4u) asm volatile("global_load_dwordx4 %0, %1, off offset:2048 sc0 sc1" : "=v"(V2) : "v"(p0));
      if (need &   8u) asm volatile("global_load_dwordx4 %0, %1, off offset:3072 sc0 sc1" : "=v"(V3) : "v"(p0));
      if (need &  16u) asm volatile("global_load_dwordx4 %0, %1, off sc0 sc1" : "=v"(V4) : "v"(p1));
      if (need &  32u) asm volatile("global_load_dwordx4 %0, %1, off offset:1024 sc0 sc1" : "=v"(V5) : "v"(p1));
      if (need &  64u) asm volatile("global_load_dwordx4 %0, %1, off offset:2048 sc0 sc1" : "=v"(V6) : "v"(p1));
      if (need & 128u) asm volatile("global_load_dwordx4 %0, %1, off offset:3072 sc0 sc1" : "=v"(V7) : "v"(p1));
      asm volatile("s_waitcnt vmcnt(0)"
                   : "+v"(V0), "+v"(V1), "+v"(V2), "+v"(V3),
                     "+v"(V4), "+v"(V5), "+v"(V6), "+v"(V7)
                   :: "memory");

      unsigned int got = 0;
      #define CHK(j, Vj)                                                      \
        if (need & (1u << (j))) {                                             \
          const bool ok = ((((Vj)[0] ^ rt) | ((Vj)[1] ^ rt) |                 \
                            ((Vj)[2] ^ rt) | ((Vj)[3] ^ rt)) & 3u) == 0u;     \
          if (__all(ok)) got |= 1u << (j);                                    \
        }
      CHK(0, V0) CHK(1, V1) CHK(2, V2) CHK(3, V3)
      CHK(4, V4) CHK(5, V5) CHK(6, V6) CHK(7, V7)
      #undef CHK

      // FMA freshly-arrived chunks (wave-uniform control flow).
      #define DOCHUNK(j, Vj)                                                  \
        if (got & (1u << (j))) {                                              \
          float4 s4;                                                          \
          s4.x = __uint_as_float((Vj)[0]); s4.y = __uint_as_float((Vj)[1]);   \
          s4.z = __uint_as_float((Vj)[2]); s4.w = __uint_as_float((Vj)[3]);   \
          const float4 x0 = W0[lane + 64 * (j)];                              \
          const float4 x1 = W1[lane + 64 * (j)];                              \
          const float4 x2 = W2[lane + 64 * (j)];                              \
          const float4 x3 = W3[lane + 64 * (j)];                              \
          a0 = fmaf(x0.x, s4.x, a0); a0 = fmaf(x0.y, s4.y, a0);               \
          a0 = fmaf(x0.z, s4.z, a0); a0 = fmaf(x0.w, s4.w, a0);               \
          a1 = fmaf(x1.x, s4.x, a1); a1 = fmaf(x1.y, s4.y, a1);               \
          a1 = fmaf(x1.z, s4.z, a1); a1 = fmaf(x1.w, s4.w, a1);               \
          a2 = fmaf(x2.x, s4.x, a2); a2 = fmaf(x2.y, s4.y, a2);               \
          a2 = fmaf(x2.z, s4.z, a2); a2 = fmaf(x2.w, s4.w, a2);               \
          a3 = fmaf(x3.x, s4.x, a3); a3 = fmaf(x3.y, s4.y, a3);               \
          a3 = fmaf(x3.z, s4.z, a3); a3 = fmaf(x3.w, s4.w, a3);               \
        }
      DOCHUNK(0, V0) DOCHUNK(1, V1) DOCHUNK(2, V2) DOCHUNK(3, V3)
      DOCHUNK(4, V4) DOCHUNK(5, V5) DOCHUNK(6, V6) DOCHUNK(7, V7)
      #undef DOCHUNK

      need &= ~got;
      if (need && !got) __builtin_amdgcn_s_sleep(1);
    }

    // ---- butterfly reduce all 4 row sums across the wave ----
    #pragma unroll
    for (int off = 32; off > 0; off >>= 1) {
      a0 += __shfl_xor(a0, off);
      a1 += __shfl_xor(a1, off);
      a2 += __shfl_xor(a2, off);
      a3 += __shfl_xor(a3, off);
    }

    // ---- lanes 0-3: tanh/leak (sold = own register from prev step) ----
    unsigned int pkw = 0;
    if (lane < RPW) {
      const float a = (lane == 0) ? a0 : (lane == 1) ? a1 : (lane == 2) ? a2 : a3;
      const float h = tanhf(itv + a);
      const float snew = (1.0f - LEAK) * sprev + LEAK * h;
      sprev = snew;
      pkw = (__float_as_uint(snew) & ~3u) | tg;
    }
    // ---- pack 4 rows -> one tagged dwordx4; lane 0 fires it ----
    uint32x4 pk;
    pk[0] = __shfl(pkw, 0);
    pk[1] = __shfl(pkw, 1);
    pk[2] = __shfl(pkw, 2);
    pk[3] = __shfl(pkw, 3);
    if (lane == 0) {
      unsigned int* dst = sbuf + ((t + 1) & 1) * N_RES + r0;
      asm volatile("global_store_dwordx4 %0, %1, off sc0 sc1"
                   :: "v"(dst), "v"(pk) : "memory");
    }
    // ---- record state + prefetch next input term (overlap next poll) ----
    if (lane < RPW) {
      it[(size_t)t * N_RES + r0 + lane] = sprev;  // exact value for readout
      if (t + 1 < T_STEPS)
        itv = it[(size_t)(t + 1) * N_RES + r0 + lane];
    }
  }
}

// ---------------------------------------------------------------------------
// Kernel 3: out[t][o] = dot(states[t,:], rw[o,:]) + rb[o]
// ---------------------------------------------------------------------------
__global__ __launch_bounds__(256) void readout_kernel(
    const float* __restrict__ states, const float* __restrict__ rw,
    const float* __restrict__ rb, float* __restrict__ out) {
  const int t = blockIdx.x;
  const int tid = threadIdx.x;
  const int o = tid & 63;
  const int q = tid >> 6;  // 0..3
  __shared__ float ss[N_RES];
  #pragma unroll
  for (int k = 0; k < N_RES / 256; ++k)
    ss[tid + 256 * k] = states[(size_t)t * N_RES + tid + 256 * k];
  __syncthreads();

  const float4* r4 = reinterpret_cast<const float4*>(rw + (size_t)o * N_RES + q * 512);
  float acc = 0.f;
  #pragma unroll 8
  for (int j = 0; j < 128; ++j) {
    float4 w4 = r4[j];
    const int base = q * 512 + 4 * j;
    acc = fmaf(w4.x, ss[base + 0], acc);
    acc = fmaf(w4.y, ss[base + 1], acc);
    acc = fmaf(w4.z, ss[base + 2], acc);
    acc = fmaf(w4.w, ss[base + 3], acc);
  }
  __shared__ float red[256];
  red[tid] = acc;
  __syncthreads();
  if (tid < 64) {
    float v = red[tid] + red[tid + 64] + red[tid + 128] + red[tid + 192];
    out[(size_t)t * N_OUT + tid] = v + rb[tid];
  }
}

// ---------------------------------------------------------------------------
extern "C" void kernel_launch(void* const* d_in, const int* in_sizes, int n_in,
                              void* d_out, int out_size, void* d_ws, size_t ws_size,
                              hipStream_t stream) {
  const float* u     = (const float*)d_in[0];  // [4096, 64]
  const float* noise = (const float*)d_in[1];  // [4096, 2048]
  const float* W_in  = (const float*)d_in[2];  // [2048, 64]
  const float* W     = (const float*)d_in[3];  // [2048, 2048]
  const float* rw    = (const float*)d_in[4];  // [64, 2048]
  const float* rb    = (const float*)d_in[5];  // [64]
  float* out = (float*)d_out;                  // [4096, 64]

  float* it = (float*)d_ws;  // 32 MB: input terms, overwritten with states
  unsigned int* sbuf =
      (unsigned int*)((char*)d_ws + (size_t)T_STEPS * N_RES * sizeof(float));

  // Zero both tagged state buffers every call (tag 0 == initial zero state;
  // ws is not re-poisoned between replays; end-of-run tags must be reset).
  hipMemsetAsync(sbuf, 0, 2 * N_RES * sizeof(unsigned int), stream);

  input_terms_kernel<<<T_STEPS, 256, 0, stream>>>(u, noise, W_in, it);

  void* args[] = {(void*)&W, (void*)&it, (void*)&sbuf};
  hipLaunchCooperativeKernel((void*)reservoir_kernel, dim3(NWG), dim3(64),
                             args, 0, stream);

  readout_kernel<<<T_STEPS, 256, 0, stream>>>(it, rw, rb, out);
}

// Round 12
// 12853.943 us; speedup vs baseline: 1.3160x; 1.3160x over previous
//
#include <hip/hip_runtime.h>

#define T_STEPS 4096
#define N_RES   2048
#define N_IN    64
#define N_OUT   64
#define LEAK    0.3f
#define NOISE_S 0.01f

#define NWG      256     // reservoir WGs (1 per CU)
#define RPW      8       // rows per WG
#define RPWAVE   2       // rows per compute wave
#define NTHREADS 320     // waves 0-3: compute+poll (R4 structure); wave 4: writer

typedef unsigned int uint32x4 __attribute__((ext_vector_type(4)));

// ---------------------------------------------------------------------------
// Kernel 1: it[t][n] = dot(u[t,:], W_in[n,:]) + 0.01*noise[t][n]
// ---------------------------------------------------------------------------
__global__ __launch_bounds__(256) void input_terms_kernel(
    const float* __restrict__ u, const float* __restrict__ noise,
    const float* __restrict__ W_in, float* __restrict__ it) {
  const int t = blockIdx.x;
  const int tid = threadIdx.x;
  __shared__ float su[N_IN];
  if (tid < N_IN) su[tid] = u[(size_t)t * N_IN + tid];
  __syncthreads();
  #pragma unroll
  for (int k = 0; k < N_RES / 256; ++k) {
    const int n = tid + 256 * k;
    const float4* wr = reinterpret_cast<const float4*>(W_in + (size_t)n * N_IN);
    float acc = 0.f;
    #pragma unroll
    for (int j = 0; j < N_IN / 4; ++j) {
      float4 w4 = wr[j];
      acc = fmaf(w4.x, su[4 * j + 0], acc);
      acc = fmaf(w4.y, su[4 * j + 1], acc);
      acc = fmaf(w4.z, su[4 * j + 2], acc);
      acc = fmaf(w4.w, su[4 * j + 3], acc);
    }
    it[(size_t)t * N_RES + n] = acc + NOISE_S * noise[(size_t)t * N_RES + n];
  }
}

// ---------------------------------------------------------------------------
// Kernel 2: persistent recurrence — R4 structure + clean-vmcnt pollers.
//
// 256 WGs x 320 threads. Waves 0-3 (= R4's 256 threads): compute 2 rows
// each, write tagged own values into next LDS buffer + raw values into
// stg_raw, then POLL s_{t+1} (2 x 16B groups per thread, own groups
// skipped). Their ONLY global-memory ops are the 2 poll loads, so the
// poll's vmcnt(0) waits on nothing else (R4's pollers had an HBM record
// store + prefetch load outstanding — ordered vmcnt drained them first,
// ~0.5-0.9us/step of hidden serial latency; R5-R10 made this worse, never
// better). Wave 4 (writer): after barrier1 packs the WG's 8 tagged words
// from LDS and fires the 2 broadcast dwordx4 stores (single producer per
// 16B group -> atomic flip), records it[t] from stg_raw, prefetches
// it[t+1] into stg_it. All its slow HBM ops overlap the poll window.
//
// Tag protocol (R4-proven): state word = fp32 bits, low 2 mantissa bits =
// (step & 3); a WG stores s_{t+1} only after its poll of s_t completed
// (poll_t ends at barrier2 of step t-1 < broadcast at barrier1 of step t),
// so skew <= 2 steps and mod-4 tags disambiguate; <= 3 ulp perturbation
// (absmax steady at 3.9e-3 << 2.17e-2). s_0 = zeros in LDS, never polled.
// Two barriers per step, same as R4.
// ---------------------------------------------------------------------------
__global__ __launch_bounds__(NTHREADS, 1) void reservoir_kernel(
    const float* __restrict__ W, float* __restrict__ it,
    unsigned int* sbuf) {
  const int wg = blockIdx.x;
  const int tid = threadIdx.x;
  const int wave = tid >> 6;       // 0..4
  const int lane = tid & 63;
  const int R = wg * RPW;

  __shared__ float Wl[RPW * N_RES];   // 64 KB
  __shared__ float ls[2][N_RES];      // 16 KB state double buffer
  __shared__ float stg_raw[RPW];      // untagged snew (writer -> it[] record)
  __shared__ float stg_it[2][RPW];    // staged input terms (writer -> compute)

  // Stage this WG's 8 W rows into LDS once.
  {
    const float4* Wg = reinterpret_cast<const float4*>(W + (size_t)R * N_RES);
    float4* Wd = reinterpret_cast<float4*>(Wl);
    for (int idx = tid; idx < RPW * N_RES / 4; idx += NTHREADS)
      Wd[idx] = Wg[idx];
  }
  // s_0 = zeros (reset_state=True) — never polled.
  for (int idx = tid; idx < N_RES; idx += NTHREADS) ls[0][idx] = 0.f;
  if (wave == 4 && lane < RPW) stg_it[0][lane] = it[R + lane];
  __syncthreads();

  if (wave < 4) {
    // ============== compute + poll waves (R4's 256 threads) ==============
    const int r0 = R + wave * RPWAVE;
    const float4* W0 = reinterpret_cast<const float4*>(Wl + (size_t)(RPWAVE * wave + 0) * N_RES);
    const float4* W1 = reinterpret_cast<const float4*>(Wl + (size_t)(RPWAVE * wave + 1) * N_RES);

    // Poll groups: g0 = tid, g1 = tid + 256 (16B each). Group g belongs to
    // WG g>>1; own groups are filled locally, skip them.
    const bool own0 = ((tid >> 1) == wg);
    const bool own1 = (((tid + 256) >> 1) == wg);
    const unsigned int own_mask = (own0 ? 1u : 0u) | (own1 ? 2u : 0u);

    for (unsigned int t = 0; t < T_STEPS; ++t) {
      const float* cur = ls[t & 1];
      float* nxt = ls[(t + 1) & 1];
      unsigned int* swb = sbuf + ((t + 1) & 1) * N_RES;

      // ---- two dot products per wave (conflict-free b128 LDS reads) ----
      const float4* S4 = reinterpret_cast<const float4*>(cur);
      float a0 = 0.f, a1 = 0.f;
      #pragma unroll
      for (int j = 0; j < 8; ++j) {
        const float4 s4 = S4[lane + 64 * j];
        const float4 x0 = W0[lane + 64 * j];
        const float4 x1 = W1[lane + 64 * j];
        a0 = fmaf(x0.x, s4.x, a0); a0 = fmaf(x0.y, s4.y, a0);
        a0 = fmaf(x0.z, s4.z, a0); a0 = fmaf(x0.w, s4.w, a0);
        a1 = fmaf(x1.x, s4.x, a1); a1 = fmaf(x1.y, s4.y, a1);
        a1 = fmaf(x1.z, s4.z, a1); a1 = fmaf(x1.w, s4.w, a1);
      }
      #pragma unroll
      for (int off = 32; off > 0; off >>= 1) {
        a0 += __shfl_xor(a0, off);
        a1 += __shfl_xor(a1, off);
      }

      // ---- lanes 0,1: finalize; write tagged -> nxt, raw -> stg_raw ----
      const unsigned int tg = (t + 1) & 3u;
      if (lane < RPWAVE) {
        const float a = lane ? a1 : a0;
        const float itv = stg_it[t & 1][wave * RPWAVE + lane];
        const float h = tanhf(itv + a);
        const float sold = cur[r0 + lane];
        const float snew = (1.0f - LEAK) * sold + LEAK * h;
        nxt[r0 + lane] = __uint_as_float((__float_as_uint(snew) & ~3u) | tg);
        stg_raw[wave * RPWAVE + lane] = snew;
      }
      __syncthreads();  // barrier1: own tagged words + stg_raw visible

      // ---- poll s_{t+1}: ONLY global ops these waves ever issue ----
      if (t + 1 < T_STEPS) {
        const char* p0 = (const char*)swb + tid * 16;
        const char* p1 = p0 + 4096;
        uint32x4* nxt16 = reinterpret_cast<uint32x4*>(nxt);
        unsigned int need = 3u & ~own_mask;
        while (need) {
          uint32x4 va, vb;
          if (need == 3u) {
            asm volatile(
                "global_load_dwordx4 %0, %2, off sc0 sc1\n\t"
                "global_load_dwordx4 %1, %3, off sc0 sc1\n\t"
                "s_waitcnt vmcnt(0)"
                : "=&v"(va), "=&v"(vb) : "v"(p0), "v"(p1) : "memory");
            if ((((va[0] ^ tg) | (va[1] ^ tg) | (va[2] ^ tg) | (va[3] ^ tg)) & 3u) == 0u) {
              nxt16[tid] = va; need &= ~1u;
            }
            if ((((vb[0] ^ tg) | (vb[1] ^ tg) | (vb[2] ^ tg) | (vb[3] ^ tg)) & 3u) == 0u) {
              nxt16[tid + 256] = vb; need &= ~2u;
            }
          } else if (need == 1u) {
            asm volatile(
                "global_load_dwordx4 %0, %1, off sc0 sc1\n\t"
                "s_waitcnt vmcnt(0)"
                : "=&v"(va) : "v"(p0) : "memory");
            if ((((va[0] ^ tg) | (va[1] ^ tg) | (va[2] ^ tg) | (va[3] ^ tg)) & 3u) == 0u) {
              nxt16[tid] = va; need = 0u;
            }
          } else {
            asm volatile(
                "global_load_dwordx4 %0, %1, off sc0 sc1\n\t"
                "s_waitcnt vmcnt(0)"
                : "=&v"(vb) : "v"(p1) : "memory");
            if ((((vb[0] ^ tg) | (vb[1] ^ tg) | (vb[2] ^ tg) | (vb[3] ^ tg)) & 3u) == 0u) {
              nxt16[tid + 256] = vb; need = 0u;
            }
          }
          if (need) __builtin_amdgcn_s_sleep(1);
        }
      }
      __syncthreads();  // barrier2: nxt complete for step t+1
    }
  } else {
    // =================== writer wave (wave 4) ===================
    // All slow HBM ops live here, overlapped with the pollers' window.
    for (unsigned int t = 0; t < T_STEPS; ++t) {
      __syncthreads();  // barrier1
      float* nxt = ls[(t + 1) & 1];
      unsigned int* swb = sbuf + ((t + 1) & 1) * N_RES;
      // Broadcast: lanes 0,1 each pack one 16B group from LDS and fire it.
      if (lane < 2) {
        uint32x4 pk;
        #pragma unroll
        for (int j = 0; j < 4; ++j)
          pk[j] = __float_as_uint(nxt[R + 4 * lane + j]);
        unsigned int* dst = swb + R + 4 * lane;
        asm volatile("global_store_dwordx4 %0, %1, off sc0 sc1"
                     :: "v"(dst), "v"(pk) : "memory");
      }
      // Record exact states + prefetch next input terms into LDS staging.
      if (lane < RPW) {
        it[(size_t)t * N_RES + R + lane] = stg_raw[lane];
        if (t + 1 < T_STEPS)
          stg_it[(t + 1) & 1][lane] = it[(size_t)(t + 1) * N_RES + R + lane];
      }
      __syncthreads();  // barrier2
    }
  }
}

// ---------------------------------------------------------------------------
// Kernel 3: out[t][o] = dot(states[t,:], rw[o,:]) + rb[o]
// ---------------------------------------------------------------------------
__global__ __launch_bounds__(256) void readout_kernel(
    const float* __restrict__ states, const float* __restrict__ rw,
    const float* __restrict__ rb, float* __restrict__ out) {
  const int t = blockIdx.x;
  const int tid = threadIdx.x;
  const int o = tid & 63;
  const int q = tid >> 6;  // 0..3
  __shared__ float ss[N_RES];
  #pragma unroll
  for (int k = 0; k < N_RES / 256; ++k)
    ss[tid + 256 * k] = states[(size_t)t * N_RES + tid + 256 * k];
  __syncthreads();

  const float4* r4 = reinterpret_cast<const float4*>(rw + (size_t)o * N_RES + q * 512);
  float acc = 0.f;
  #pragma unroll 8
  for (int j = 0; j < 128; ++j) {
    float4 w4 = r4[j];
    const int base = q * 512 + 4 * j;
    acc = fmaf(w4.x, ss[base + 0], acc);
    acc = fmaf(w4.y, ss[base + 1], acc);
    acc = fmaf(w4.z, ss[base + 2], acc);
    acc = fmaf(w4.w, ss[base + 3], acc);
  }
  __shared__ float red[256];
  red[tid] = acc;
  __syncthreads();
  if (tid < 64) {
    float v = red[tid] + red[tid + 64] + red[tid + 128] + red[tid + 192];
    out[(size_t)t * N_OUT + tid] = v + rb[tid];
  }
}

// ---------------------------------------------------------------------------
extern "C" void kernel_launch(void* const* d_in, const int* in_sizes, int n_in,
                              void* d_out, int out_size, void* d_ws, size_t ws_size,
                              hipStream_t stream) {
  const float* u     = (const float*)d_in[0];  // [4096, 64]
  const float* noise = (const float*)d_in[1];  // [4096, 2048]
  const float* W_in  = (const float*)d_in[2];  // [2048, 64]
  const float* W     = (const float*)d_in[3];  // [2048, 2048]
  const float* rw    = (const float*)d_in[4];  // [64, 2048]
  const float* rb    = (const float*)d_in[5];  // [64]
  float* out = (float*)d_out;                  // [4096, 64]

  float* it = (float*)d_ws;  // 32 MB: input terms, overwritten with states
  unsigned int* sbuf =
      (unsigned int*)((char*)d_ws + (size_t)T_STEPS * N_RES * sizeof(float));

  // Zero both tagged state buffers every call (0xAA poison would alias tag
  // bits; end-of-run tags must be reset for deterministic replays).
  hipMemsetAsync(sbuf, 0, 2 * N_RES * sizeof(unsigned int), stream);

  input_terms_kernel<<<T_STEPS, 256, 0, stream>>>(u, noise, W_in, it);

  void* args[] = {(void*)&W, (void*)&it, (void*)&sbuf};
  hipLaunchCooperativeKernel((void*)reservoir_kernel, dim3(NWG), dim3(NTHREADS),
                             args, 0, stream);

  readout_kernel<<<T_STEPS, 256, 0, stream>>>(it, rw, rb, out);
}